// Round 13
// baseline (132.177 us; speedup 1.0000x reference)
//
#include <hip/hip_runtime.h>
#include <math.h>

// Problem constants
#define BB 2
#define HH 64
#define WW 64
#define DM 128
#define EE 256
#define NN 16
#define RR 8
#define HW (HH*WW)          // 4096
#define CH 16               // k2a rows per pipeline chunk
#define NCH (HH/CH)         // 4 chunks

__device__ __forceinline__ float gelu_exact(float v) {
    return 0.5f * v * (1.f + erff(v * 0.70710678118654752440f));
}
__device__ __forceinline__ float softplus_f(float v) {
    return fmaxf(v, 0.f) + log1pf(__expf(-fabsf(v)));
}

template<int S>
__device__ __forceinline__ float dpp_shr0(float x) {
    return __int_as_float(__builtin_amdgcn_update_dpp(
        0, __float_as_int(x), 0x110 | S, 0xF, 0xF, false));
}

// ---------------------------------------------------------------------------
// K1a: u = gelu(x@ipw^T + ipb) -> u_t[B,E,H,W] AND u_rm[B,H,W,E].
// grid = 128 rows x 8 e-chunks of 32. u_rm written via LDS transpose.
// ---------------------------------------------------------------------------
__global__ __launch_bounds__(256) void k1a_u(
    const float* __restrict__ x,
    const float* __restrict__ ipw, const float* __restrict__ ipb,
    float* __restrict__ u_t, float* __restrict__ u_rm)
{
    __shared__ float xs[64][129];
    __shared__ float ut[64][36];

    const int blk = blockIdx.x;
    const int row = blk >> 3;            // b*64 + i
    const int ec  = blk & 7;
    const int b = row >> 6, i = row & 63;
    const int t = threadIdx.x;
    const int w = __builtin_amdgcn_readfirstlane(t >> 6);
    const int j = t & 63;

    const float* xrow = x + (size_t)row * (WW * DM);
    for (int idx = t; idx < WW * DM; idx += 256)
        xs[idx >> 7][idx & 127] = xrow[idx];
    __syncthreads();

    const int e0 = ec * 32 + w * 8;
    float acc[8];
    #pragma unroll
    for (int ee = 0; ee < 8; ++ee) acc[ee] = 0.f;

    for (int k = 0; k < DM; ++k) {
        const float xv = xs[j][k];
        #pragma unroll
        for (int ee = 0; ee < 8; ++ee)
            acc[ee] = fmaf(xv, ipw[(e0 + ee) * DM + k], acc[ee]);
    }
    #pragma unroll
    for (int ee = 0; ee < 8; ++ee) {
        const int e = e0 + ee;
        const float g = gelu_exact(acc[ee] + ipb[e]);
        u_t[(((size_t)(b * EE + e) * HH + i) << 6) + j] = g;
        ut[j][w * 8 + ee] = g;
    }
    __syncthreads();

    // transpose writeout: u_rm[(row*64 + j)*256 + ec*32 + (0..31)]
    {
        const int j2 = t >> 2, q = t & 3;
        float* dst = u_rm + ((size_t)(row * 64 + j2) << 8) + ec * 32 + q * 8;
        *(float4*)(dst)     = *(const float4*)&ut[j2][q * 8];
        *(float4*)(dst + 4) = *(const float4*)&ut[j2][q * 8 + 4];
    }
}

// ---------------------------------------------------------------------------
// K1b (fused, replaces k1b1+k1b2): grid = 128 rows x 4 j-quarters = 512
// blocks, 256 thr. Per e-chunk of 64: stage xpw chunk + u chunk (from u_rm,
// dense coalesced float4), GEMM dbc[48][16] from LDS; then Bm/Cm split and
// softplus deltas, all in-block (no dbc_g round trip).
// ---------------------------------------------------------------------------
__global__ __launch_bounds__(256) void k1b_fused(
    const float* __restrict__ u_rm,
    const float* __restrict__ xpw, const float* __restrict__ xpb,
    const float* __restrict__ dtTw, const float* __restrict__ dtTb,
    const float* __restrict__ dtLw, const float* __restrict__ dtLb,
    float* __restrict__ dT_t, float* __restrict__ dL_t,
    float* __restrict__ Bm_t, float* __restrict__ Cm_t)
{
    __shared__ float xw[48][66];
    __shared__ float uu[16][66];
    __shared__ float dbcs[48][17];

    const int blk = blockIdx.x;          // (b*64+i)*4 + jq
    const int jq = blk & 3;
    const int row = blk >> 2;
    const int b = row >> 6, i = row & 63;
    const int j0 = jq * 16;
    const int t = threadIdx.x;
    const int jj = t & 15, cg = t >> 4;  // cg 0..15; channels 3cg..3cg+2

    float a0 = 0.f, a1 = 0.f, a2 = 0.f;

    for (int ch = 0; ch < 4; ++ch) {
        // stage xpw chunk: 48 x 64 floats (12 float4/thread-ish)
        for (int idx = t; idx < 48 * 16; idx += 256) {
            const int c = idx >> 4, e4 = idx & 15;
            *(float4*)&xw[c][4 * e4] =
                *(const float4*)(xpw + (size_t)c * EE + ch * 64 + 4 * e4);
        }
        // stage u chunk from u_rm: 16 x 64 floats
        for (int idx = t; idx < 16 * 16; idx += 256) {
            const int j2 = idx >> 4, e4 = idx & 15;
            *(float4*)&uu[j2][4 * e4] =
                *(const float4*)(u_rm + ((size_t)(row * 64 + j0 + j2) << 8)
                                 + ch * 64 + 4 * e4);
        }
        __syncthreads();

        for (int e4 = 0; e4 < 16; ++e4) {
            const float4 uv = *(const float4*)&uu[jj][4 * e4];
            const float4 w0 = *(const float4*)&xw[3 * cg + 0][4 * e4];
            const float4 w1 = *(const float4*)&xw[3 * cg + 1][4 * e4];
            const float4 w2 = *(const float4*)&xw[3 * cg + 2][4 * e4];
            a0 = fmaf(uv.x, w0.x, a0); a0 = fmaf(uv.y, w0.y, a0);
            a0 = fmaf(uv.z, w0.z, a0); a0 = fmaf(uv.w, w0.w, a0);
            a1 = fmaf(uv.x, w1.x, a1); a1 = fmaf(uv.y, w1.y, a1);
            a1 = fmaf(uv.z, w1.z, a1); a1 = fmaf(uv.w, w1.w, a1);
            a2 = fmaf(uv.x, w2.x, a2); a2 = fmaf(uv.y, w2.y, a2);
            a2 = fmaf(uv.z, w2.z, a2); a2 = fmaf(uv.w, w2.w, a2);
        }
        __syncthreads();
    }

    dbcs[3 * cg + 0][jj] = a0 + xpb[3 * cg + 0];
    dbcs[3 * cg + 1][jj] = a1 + xpb[3 * cg + 1];
    dbcs[3 * cg + 2][jj] = a2 + xpb[3 * cg + 2];
    __syncthreads();

    // Bm / Cm: thread (n = cg, jj)
    {
        const int n = cg;
        Bm_t[(((size_t)(b * NN + n) * HH + i) << 6) + j0 + jj] = dbcs[16 + n][jj];
        Cm_t[(((size_t)(b * NN + n) * HH + i) << 6) + j0 + jj] = dbcs[32 + n][jj];
    }

    // deltas: thread (eg = cg, jj) -> e = eg*16 + (0..15)
    {
        float dtv[8], dlv[8];
        #pragma unroll
        for (int r = 0; r < 8; ++r) { dtv[r] = dbcs[r][jj]; dlv[r] = dbcs[8 + r][jj]; }
        #pragma unroll 4
        for (int ee = 0; ee < 16; ++ee) {
            const int e = cg * 16 + ee;
            float sT = dtTb[e], sL = dtLb[e];
            #pragma unroll
            for (int r = 0; r < 8; ++r) {
                sT = fmaf(dtv[r], dtTw[e * RR + r], sT);
                sL = fmaf(dlv[r], dtLw[e * RR + r], sL);
            }
            dT_t[(((size_t)(b * EE + e) * HH + i) << 6) + j0 + jj] = softplus_f(sT);
            dL_t[(((size_t)(b * EE + e) * HH + i) << 6) + j0 + jj] = softplus_f(sL);
        }
    }
}

// ---------------------------------------------------------------------------
// K2a: wavefront scan, LDS-pipelined (unchanged from R11).
// ---------------------------------------------------------------------------
__device__ __forceinline__ float row_scan_raw(
    float4 dT4, float4 dL4, float4 u4, float4 bm4, float4 cm4,
    float AT2, float AL2, float* h, int c, int jj)
{
    const float dTv[4] = {dT4.x, dT4.y, dT4.z, dT4.w};
    const float dLv[4] = {dL4.x, dL4.y, dL4.z, dL4.w};
    const float uv[4]  = {u4.x,  u4.y,  u4.z,  u4.w};
    const float bmv[4] = {bm4.x, bm4.y, bm4.z, bm4.w};
    const float cmv[4] = {cm4.x, cm4.y, cm4.z, cm4.w};

    float cumA[4], cumB[4];
    {
        const float aT = exp2f(dTv[0] * AT2);
        cumA[0] = exp2f(dLv[0] * AL2);
        cumB[0] = fmaf(aT, h[0], (dTv[0] + dLv[0]) * bmv[0] * uv[0]);
    }
    #pragma unroll
    for (int k = 1; k < 4; ++k) {
        const float aT = exp2f(dTv[k] * AT2);
        const float aL = exp2f(dLv[k] * AL2);
        const float bk = fmaf(aT, h[k], (dTv[k] + dLv[k]) * bmv[k] * uv[k]);
        cumB[k] = fmaf(aL, cumB[k - 1], bk);
        cumA[k] = aL * cumA[k - 1];
    }

    float Ag = cumA[3], Bg = cumB[3];
    { const float uA = dpp_shr0<1>(Ag), uB = dpp_shr0<1>(Bg);
      Bg = fmaf(Ag, uB, Bg); Ag *= (jj >= 1) ? uA : 1.f; }
    { const float uA = dpp_shr0<2>(Ag), uB = dpp_shr0<2>(Bg);
      Bg = fmaf(Ag, uB, Bg); Ag *= (jj >= 2) ? uA : 1.f; }
    { const float uA = dpp_shr0<4>(Ag), uB = dpp_shr0<4>(Bg);
      Bg = fmaf(Ag, uB, Bg); Ag *= (jj >= 4) ? uA : 1.f; }
    { const float uB = dpp_shr0<8>(Bg);
      Bg = fmaf(Ag, uB, Bg); }
    const float pB = dpp_shr0<1>(Bg);

    float g[4];
    #pragma unroll
    for (int k = 0; k < 4; ++k) {
        h[k] = fmaf(cumA[k], pB, cumB[k]);
        g[k] = h[k] * cmv[k];
    }
    #pragma unroll
    for (int k = 0; k < 4; ++k) {
        g[k] += __shfl_xor(g[k], 16, 64);
        g[k] += __shfl_xor(g[k], 32, 64);
    }
    return (c == 0) ? g[0] : (c == 1) ? g[1] : (c == 2) ? g[2] : g[3];
}

__global__ __launch_bounds__(256, 2) void k2a_scan(
    const float* __restrict__ u_t, const float* __restrict__ dT_t,
    const float* __restrict__ dL_t, const float* __restrict__ Bm_t,
    const float* __restrict__ Cm_t, const float* __restrict__ ATl,
    const float* __restrict__ ALl, const float* __restrict__ Dp,
    float* __restrict__ ys_t)
{
    __shared__ float sdT[2][CH][64];
    __shared__ float sdL[2][CH][64];
    __shared__ float su [2][CH][64];
    __shared__ float parts[2][4][CH][64];

    const int be = blockIdx.x;           // b*256 + e
    const int b = be >> 8, e = be & 255;
    const int t = threadIdx.x;
    const int w = __builtin_amdgcn_readfirstlane(t >> 6);
    const int lane = t & 63;
    const int c = lane >> 4, jj = lane & 15;
    const int n = w * 4 + c;
    const int col = 4 * jj + c;

    const float LOG2E = 1.44269504088896340736f;
    const float AT2 = -__expf(ATl[e * NN + n]) * LOG2E;
    const float AL2 = -__expf(ALl[e * NN + n]) * LOG2E;
    const float De = Dp[e];

    const float* dTg = dT_t + ((size_t)be << 12);
    const float* dLg = dL_t + ((size_t)be << 12);
    const float* ug  = u_t  + ((size_t)be << 12);
    const float* bmp = Bm_t + ((size_t)(b * NN + n) << 12) + 4 * jj;
    const float* cmp = Cm_t + ((size_t)(b * NN + n) << 12) + 4 * jj;

    const int srow = t >> 4;
    const int scol = (t & 15) << 2;

    const int fcol = t & 63;
    const float* uf = ug + fcol;
    float* ysf = ys_t + ((size_t)be << 12) + fcol;

    float4 ldT, ldL, lu;
    {
        const size_t off = ((size_t)srow << 6) + scol;
        ldT = *(const float4*)(dTg + off);
        ldL = *(const float4*)(dLg + off);
        lu  = *(const float4*)(ug  + off);
        *(float4*)&sdT[0][srow][scol] = ldT;
        *(float4*)&sdL[0][srow][scol] = ldL;
        *(float4*)&su [0][srow][scol] = lu;
    }
    __syncthreads();

    float4 bm4 = *(const float4*)(bmp);
    float4 cm4 = *(const float4*)(cmp);

    float h[4] = {0.f, 0.f, 0.f, 0.f};

    for (int ch = 0; ch < NCH; ++ch) {
        const int buf = ch & 1;

        if (ch + 1 < NCH) {
            const size_t off = ((size_t)((ch + 1) * CH + srow) << 6) + scol;
            ldT = *(const float4*)(dTg + off);
            ldL = *(const float4*)(dLg + off);
            lu  = *(const float4*)(ug  + off);
            __builtin_amdgcn_sched_barrier(0);
        }

        #pragma unroll
        for (int r = 0; r < CH; ++r) {
            const int i = ch * CH + r;
            const int ipn = (i + 1 < HH) ? i + 1 : i;
            const float4 bm4n = *(const float4*)(bmp + (ipn << 6));
            const float4 cm4n = *(const float4*)(cmp + (ipn << 6));

            const float4 dT4 = *(const float4*)&sdT[buf][r][4 * jj];
            const float4 dL4 = *(const float4*)&sdL[buf][r][4 * jj];
            const float4 u4  = *(const float4*)&su [buf][r][4 * jj];

            parts[buf][w][r][col] =
                row_scan_raw(dT4, dL4, u4, bm4, cm4, AT2, AL2, h, c, jj);

            bm4 = bm4n; cm4 = cm4n;
        }

        if (ch + 1 < NCH) {
            *(float4*)&sdT[buf ^ 1][srow][scol] = ldT;
            *(float4*)&sdL[buf ^ 1][srow][scol] = ldL;
            *(float4*)&su [buf ^ 1][srow][scol] = lu;
        }
        __syncthreads();

        #pragma unroll
        for (int q = 0; q < 4; ++q) {
            const int r = (t >> 6) * 4 + q;
            const int i = ch * CH + r;
            const float s = ((parts[buf][0][r][fcol] + parts[buf][1][r][fcol]) +
                             (parts[buf][2][r][fcol] + parts[buf][3][r][fcol]));
            ysf[i << 6] = gelu_exact(fmaf(uf[i << 6], De, s));
        }
    }
}

// ---------------------------------------------------------------------------
// K3: out projection. grid = 128 rows x 4 d-chunks. (unchanged)
// ---------------------------------------------------------------------------
__global__ __launch_bounds__(256) void k3_outproj(
    const float* __restrict__ ys_t,
    const float* __restrict__ ow, const float* __restrict__ ob,
    float* __restrict__ out)
{
    __shared__ float ysL[64][65];

    const int blk = blockIdx.x;
    const int row = blk >> 2;
    const int dc  = blk & 3;
    const int b = row >> 6, i = row & 63;
    const int t = threadIdx.x;
    const int w = __builtin_amdgcn_readfirstlane(t >> 6);
    const int j = t & 63;
    const int d0 = dc * 32 + w * 8;

    float acc[8];
    #pragma unroll
    for (int dd = 0; dd < 8; ++dd) acc[dd] = 0.f;

    for (int ch = 0; ch < 4; ++ch) {
        __syncthreads();
        for (int idx = t; idx < 64 * 64; idx += 256) {
            const int ee = idx >> 6, jj = idx & 63;
            ysL[ee][jj] = ys_t[(((size_t)(b * EE + ch * 64 + ee) * HH + i) << 6) + jj];
        }
        __syncthreads();
        for (int e64 = 0; e64 < 64; ++e64) {
            const float yv = ysL[e64][j];
            const int e = ch * 64 + e64;
            #pragma unroll
            for (int dd = 0; dd < 8; ++dd)
                acc[dd] = fmaf(ow[(d0 + dd) * EE + e], yv, acc[dd]);
        }
    }

    float* orow = out + (size_t)row * (WW * DM) + (size_t)j * DM + d0;
    #pragma unroll
    for (int dd = 0; dd < 8; ++dd) orow[dd] = acc[dd] + ob[d0 + dd];
}

extern "C" void kernel_launch(void* const* d_in, const int* in_sizes, int n_in,
                              void* d_out, int out_size, void* d_ws, size_t ws_size,
                              hipStream_t stream) {
    const float* x    = (const float*)d_in[0];
    const float* ipw  = (const float*)d_in[1];
    const float* ipb  = (const float*)d_in[2];
    const float* xpw  = (const float*)d_in[3];
    const float* xpb  = (const float*)d_in[4];
    const float* dtTw = (const float*)d_in[5];
    const float* dtTb = (const float*)d_in[6];
    const float* dtLw = (const float*)d_in[7];
    const float* dtLb = (const float*)d_in[8];
    const float* ATl  = (const float*)d_in[9];
    const float* ALl  = (const float*)d_in[10];
    const float* Dp   = (const float*)d_in[11];
    const float* ow   = (const float*)d_in[12];
    const float* ob   = (const float*)d_in[13];
    float* out = (float*)d_out;

    float* ws    = (float*)d_ws;
    float* u_t   = ws;
    float* dT_t  = u_t  + (size_t)BB * EE * HW;
    float* dL_t  = dT_t + (size_t)BB * EE * HW;
    float* ys_t  = dL_t + (size_t)BB * EE * HW;
    float* Bm_t  = ys_t + (size_t)BB * EE * HW;
    float* Cm_t  = Bm_t + (size_t)BB * NN * HW;
    float* u_rm  = Cm_t + (size_t)BB * NN * HW;   // [B,H,W,E] = 8MB

    k1a_u<<<BB * HH * 8, 256, 0, stream>>>(x, ipw, ipb, u_t, u_rm);
    k1b_fused<<<BB * HH * 4, 256, 0, stream>>>(u_rm, xpw, xpb, dtTw, dtTb,
                                               dtLw, dtLb, dT_t, dL_t, Bm_t, Cm_t);
    k2a_scan<<<BB * EE, 256, 0, stream>>>(u_t, dT_t, dL_t, Bm_t, Cm_t,
                                          ATl, ALl, Dp, ys_t);
    k3_outproj<<<BB * HH * 4, 256, 0, stream>>>(ys_t, ow, ob, out);
}